// Round 3
// baseline (513.702 us; speedup 1.0000x reference)
//
#include <hip/hip_runtime.h>
#include <hip/hip_bf16.h>
#include <math.h>

#define S_LEN 4096
#define HIDDEN 2048
#define NH 16
#define QLORA 768
#define KVLORA 512
#define DROPE 64
#define DV 128
#define TOPK 1024
#define DQK 192

typedef __attribute__((ext_vector_type(4))) float f32x4;
typedef __attribute__((ext_vector_type(8))) __bf16 bf16x8;
typedef __attribute__((ext_vector_type(8))) unsigned short ushort8;
typedef unsigned short u16;
typedef unsigned int u32;

__device__ __forceinline__ u16 f2bf(float f) {
    union { float f; u32 u; } v; v.f = f;
    u32 r = v.u + 0x7fffu + ((v.u >> 16) & 1u);
    return (u16)(r >> 16);
}

// ---------------- fp32 -> bf16 cast (hidden_states) ----------------
__global__ __launch_bounds__(256) void k_cast(const float* __restrict__ src,
                                              u16* __restrict__ dst, int n4) {
    int i = blockIdx.x * 256 + threadIdx.x;
    if (i >= n4) return;
    float4 v = ((const float4*)src)[i];
    union { u16 h[4]; uint2 u; } o;
    o.h[0] = f2bf(v.x); o.h[1] = f2bf(v.y);
    o.h[2] = f2bf(v.z); o.h[3] = f2bf(v.w);
    ((uint2*)dst)[i] = o.u;
}

// ---------------- YaRN cos/sin table ----------------
__global__ __launch_bounds__(256) void k_yarn(const int* __restrict__ pos_ids,
                                              float* __restrict__ cos_t,
                                              float* __restrict__ sin_t) {
    int idx = blockIdx.x * 256 + threadIdx.x;     // S*32 entries
    if (idx >= S_LEN * 32) return;
    int s = idx >> 5, i = idx & 31;
    float pos = (float)pos_ids[s];
    // angle = pos * ROPE_BASE^(-i/32) / 1024   (both /32 factors folded)
    float inv = expf(-(float)i * 0.503690489092448f) * (1.0f / 1024.0f);
    float ang = pos * inv;
    const float MS2 = 1.8132604f;                 // (0.1*ln(32)+1)^2
    float sv, cv;
    sincosf(ang, &sv, &cv);
    cos_t[idx] = cv * MS2;
    sin_t[idx] = sv * MS2;
}

// ---------------- weight transpose+cast  W[K,N] fp32 -> Wt[N,K] bf16 ----------------
__global__ __launch_bounds__(256) void k_transpose(const float* __restrict__ src,
                                                   u16* __restrict__ dst,
                                                   int K, int N) {
    __shared__ u16 t[32][33];
    int n0 = blockIdx.x * 32, k0 = blockIdx.y * 32;
    int tx = threadIdx.x & 31, ty = threadIdx.x >> 5;   // 32 x 8
    #pragma unroll
    for (int i = 0; i < 32; i += 8)
        t[ty + i][tx] = f2bf(src[(long)(k0 + ty + i) * N + n0 + tx]);
    __syncthreads();
    #pragma unroll
    for (int i = 0; i < 32; i += 8)
        dst[(long)(n0 + ty + i) * K + k0 + tx] = t[tx][ty + i];
}

// ---------------- generic bf16 GEMM: C = A[M,K] @ Bt[N,K]^T ----------------
// 128x128 tile, BK=32, 4 waves (2x2), each wave 64x64 (4x4 frags of 16x16x32)
// MODE 0: G1  col<768 -> q_lr fp32[row*768+col]; else kv_lr fp32[row*576+col-768]
// MODE 1: G2  col<2048 -> q_full bf16[(h*S+row)*192 + d]; else q_rope_raw[row*1024+c2]
// MODE 2: G3  k/v split: h=col>>8, r=col&255; r<128 -> k_buf else v_buf ([h*S+row]*128)
// MODE 3: G4  fp32 row-major out0[row*N+col]
template <int MODE>
__global__ __launch_bounds__(256) void k_gemm(const u16* __restrict__ A,
                                              const u16* __restrict__ Bt,
                                              void* __restrict__ out0,
                                              void* __restrict__ out1,
                                              int M, int N, int K) {
    __shared__ u16 lA[128 * 40];
    __shared__ u16 lB[128 * 40];
    const int bm = blockIdx.y, bn = blockIdx.x;
    const int tid = threadIdx.x;
    const int lane = tid & 63, wid = tid >> 6;
    const int wr = wid >> 1, wc = wid & 1;
    const int l15 = lane & 15, l4 = lane >> 4;

    f32x4 acc[4][4];
    #pragma unroll
    for (int i = 0; i < 4; ++i)
        #pragma unroll
        for (int j = 0; j < 4; ++j) acc[i][j] = f32x4{0.f, 0.f, 0.f, 0.f};

    const int r = tid >> 1;
    const int ko = (tid & 1) * 16;
    const long arow = (long)bm * 128 + r;
    const int bcol = bn * 128 + r;
    const u16* pA = A + arow * K + ko;
    const u16* pB = Bt + (long)bcol * K + ko;
    const bool bok = (bcol < N);

    const int nkt = K >> 5;
    for (int kt = 0; kt < nkt; ++kt) {
        uint4 a0 = *(const uint4*)(pA);
        uint4 a1 = *(const uint4*)(pA + 8);
        uint4 b0 = bok ? *(const uint4*)(pB) : uint4{0, 0, 0, 0};
        uint4 b1 = bok ? *(const uint4*)(pB + 8) : uint4{0, 0, 0, 0};
        pA += 32; pB += 32;
        *(uint4*)(&lA[r * 40 + ko]) = a0;
        *(uint4*)(&lA[r * 40 + ko + 8]) = a1;
        *(uint4*)(&lB[r * 40 + ko]) = b0;
        *(uint4*)(&lB[r * 40 + ko + 8]) = b1;
        __syncthreads();

        bf16x8 af[4], bfr[4];
        #pragma unroll
        for (int mr = 0; mr < 4; ++mr)
            af[mr] = *(const bf16x8*)(&lA[(wr * 64 + mr * 16 + l15) * 40 + l4 * 8]);
        #pragma unroll
        for (int nc = 0; nc < 4; ++nc)
            bfr[nc] = *(const bf16x8*)(&lB[(wc * 64 + nc * 16 + l15) * 40 + l4 * 8]);
        #pragma unroll
        for (int mr = 0; mr < 4; ++mr)
            #pragma unroll
            for (int nc = 0; nc < 4; ++nc)
                acc[mr][nc] = __builtin_amdgcn_mfma_f32_16x16x32_bf16(
                    af[mr], bfr[nc], acc[mr][nc], 0, 0, 0);
        __syncthreads();
    }

    const int row0 = bm * 128 + wr * 64;
    const int col0 = bn * 128 + wc * 64;
    #pragma unroll
    for (int mr = 0; mr < 4; ++mr) {
        #pragma unroll
        for (int nc = 0; nc < 4; ++nc) {
            #pragma unroll
            for (int jj = 0; jj < 4; ++jj) {
                int row = row0 + mr * 16 + l4 * 4 + jj;
                int col = col0 + nc * 16 + l15;
                if (col >= N) continue;
                float v = acc[mr][nc][jj];
                if (MODE == 0) {
                    if (col < QLORA)
                        ((float*)out0)[(long)row * QLORA + col] = v;
                    else
                        ((float*)out1)[(long)row * (KVLORA + DROPE) + (col - QLORA)] = v;
                } else if (MODE == 1) {
                    if (col < NH * DV) {
                        int h = col >> 7, d = col & 127;
                        ((u16*)out0)[((long)h * S_LEN + row) * DQK + d] = f2bf(v);
                    } else {
                        int c2 = col - NH * DV;
                        ((u16*)out1)[(long)row * (NH * DROPE) + c2] = f2bf(v);
                    }
                } else if (MODE == 2) {
                    int h = col >> 8, rr = col & 255;
                    if (rr < 128)
                        ((u16*)out0)[((long)h * S_LEN + row) * DV + rr] = f2bf(v);
                    else
                        ((u16*)out1)[((long)h * S_LEN + row) * DV + (rr - 128)] = f2bf(v);
                } else {
                    ((float*)out0)[(long)row * N + col] = v;
                }
            }
        }
    }
}

// ---------------- RMSNorm (q path, C=768) ----------------
__global__ __launch_bounds__(256) void k_rms_q(const float* __restrict__ q_lr,
                                               const float* __restrict__ w,
                                               u16* __restrict__ q_latent) {
    int s = blockIdx.x;
    const float* x = q_lr + (long)s * QLORA;
    int t = threadIdx.x;
    float v0 = x[t], v1 = x[t + 256], v2 = x[t + 512];
    float ss = v0 * v0 + v1 * v1 + v2 * v2;
    #pragma unroll
    for (int off = 32; off >= 1; off >>= 1) ss += __shfl_xor(ss, off);
    __shared__ float red[4];
    if ((t & 63) == 0) red[t >> 6] = ss;
    __syncthreads();
    ss = red[0] + red[1] + red[2] + red[3];
    float inv = rsqrtf(ss / (float)QLORA + 1e-6f);
    u16* o = q_latent + (long)s * QLORA;
    o[t]       = f2bf(v0 * inv * w[t]);
    o[t + 256] = f2bf(v1 * inv * w[t + 256]);
    o[t + 512] = f2bf(v2 * inv * w[t + 512]);
}

// ---------------- RMSNorm (kv, C=512) + k_rope rotation ----------------
__global__ __launch_bounds__(256) void k_kv_norm_rope(const float* __restrict__ kv_lr,
                                                      const float* __restrict__ w,
                                                      const float* __restrict__ cos_t,
                                                      const float* __restrict__ sin_t,
                                                      u16* __restrict__ kv_latent,
                                                      u16* __restrict__ krope) {
    int s = blockIdx.x;
    const float* x = kv_lr + (long)s * (KVLORA + DROPE);
    int t = threadIdx.x;
    float v0 = x[t], v1 = x[t + 256];
    float ss = v0 * v0 + v1 * v1;
    #pragma unroll
    for (int off = 32; off >= 1; off >>= 1) ss += __shfl_xor(ss, off);
    __shared__ float red[4];
    if ((t & 63) == 0) red[t >> 6] = ss;
    __syncthreads();
    ss = red[0] + red[1] + red[2] + red[3];
    float inv = rsqrtf(ss / (float)KVLORA + 1e-6f);
    u16* o = kv_latent + (long)s * KVLORA;
    o[t]       = f2bf(v0 * inv * w[t]);
    o[t + 256] = f2bf(v1 * inv * w[t + 256]);
    if (t < DROPE) {
        int i = t & 31;
        float c = cos_t[s * 32 + i], sn = sin_t[s * 32 + i];
        float xr = x[KVLORA + t];
        float xp = x[KVLORA + ((t < 32) ? t + 32 : t - 32)];
        float val = (t < 32) ? xr * c - xp * sn : xr * c + xp * sn;
        krope[(long)s * DROPE + t] = f2bf(val);
    }
}

// ---------------- RoPE on q_rope -> q_full[..][128..192] ----------------
__global__ __launch_bounds__(256) void k_rope_q(const u16* __restrict__ q_rope_raw,
                                                const float* __restrict__ cos_t,
                                                const float* __restrict__ sin_t,
                                                u16* __restrict__ q_full) {
    long idx = (long)blockIdx.x * 256 + threadIdx.x;  // S*16*64
    int s = (int)(idx >> 10);
    int rem = (int)(idx & 1023);
    int h = rem >> 6, j = rem & 63;
    int i = j & 31;
    float c = cos_t[s * 32 + i], sn = sin_t[s * 32 + i];
    const u16* base = q_rope_raw + (long)s * (NH * DROPE) + h * DROPE;
    union { u32 u; float f; } xr, xp;
    xr.u = ((u32)base[j]) << 16;
    xp.u = ((u32)base[(j < 32) ? j + 32 : j - 32]) << 16;
    float val = (j < 32) ? xr.f * c - xp.f * sn : xr.f * c + xp.f * sn;
    q_full[((long)h * S_LEN + s) * DQK + DV + j] = f2bf(val);
}

// ---------------- gather k_g (192-wide) and v_g ----------------
__global__ void k_gather(const int* __restrict__ idx,
                         const u16* __restrict__ k_buf,
                         const u16* __restrict__ v_buf,
                         const u16* __restrict__ krope,
                         u16* __restrict__ k_g, u16* __restrict__ v_g) {
    int j = blockIdx.x, h = blockIdx.y, t = threadIdx.x;  // 64 threads
    int src = idx[j];
    const uint4* kb = (const uint4*)(k_buf + ((long)h * S_LEN + src) * DV);
    const uint4* vb = (const uint4*)(v_buf + ((long)h * S_LEN + src) * DV);
    const uint4* kr = (const uint4*)(krope + (long)src * DROPE);
    uint4* kgp = (uint4*)(k_g + ((long)h * TOPK + j) * DQK);
    uint4* vgp = (uint4*)(v_g + ((long)h * TOPK + j) * DV);
    if (t < 16)       kgp[t] = kb[t];
    else if (t < 24)  kgp[t] = kr[t - 16];
    else if (t < 40)  vgp[t - 24] = vb[t - 24];
}

// ---------------- flash attention over gathered keys ----------------
// grid (64, 16): 64 q-rows per block per head. 4 waves, 16 q-rows each.
__global__ __launch_bounds__(256) void k_attn(const u16* __restrict__ qf,
                                              const u16* __restrict__ kg,
                                              const u16* __restrict__ vg,
                                              u16* __restrict__ attn_out) {
    __shared__ u16 lK[64 * 200];   // [key][d] pad->200
    __shared__ u16 lV[128 * 72];   // transposed [d][key] pad->72
    __shared__ u16 lP[4 * 16 * 72];// per-wave [q][key] pad->72
    const int h = blockIdx.y, qt = blockIdx.x;
    const int tid = threadIdx.x, lane = tid & 63, wid = tid >> 6;
    const int l15 = lane & 15, l4 = lane >> 4;

    bf16x8 qfr[6];
    {
        const u16* qrow = qf + ((long)h * S_LEN + qt * 64 + wid * 16 + l15) * DQK + l4 * 8;
        #pragma unroll
        for (int kd = 0; kd < 6; ++kd) qfr[kd] = *(const bf16x8*)(qrow + kd * 32);
    }
    float m[4] = {-1e30f, -1e30f, -1e30f, -1e30f};
    float l[4] = {0.f, 0.f, 0.f, 0.f};
    f32x4 acc_o[8];
    #pragma unroll
    for (int nc = 0; nc < 8; ++nc) acc_o[nc] = f32x4{0.f, 0.f, 0.f, 0.f};

    const int krow = tid >> 2, kseg = (tid & 3) * 48;
    const int vkey = tid >> 2, vseg = (tid & 3) * 32;
    const float scale = 0.07216878364870323f;  // 1/sqrt(192)

    for (int kt = 0; kt < TOPK / 64; ++kt) {
        {   // K tile stage (coalesced rows)
            const u16* src = kg + ((long)h * TOPK + kt * 64 + krow) * DQK + kseg;
            u16* dst = &lK[krow * 200 + kseg];
            #pragma unroll
            for (int u = 0; u < 6; ++u)
                *(uint4*)(dst + u * 8) = *(const uint4*)(src + u * 8);
        }
        {   // V tile stage, transposed into [d][key]
            const u16* src = vg + ((long)h * TOPK + kt * 64 + vkey) * DV + vseg;
            ushort8 dv[4];
            #pragma unroll
            for (int u = 0; u < 4; ++u) dv[u] = *(const ushort8*)(src + u * 8);
            #pragma unroll
            for (int u = 0; u < 4; ++u)
                #pragma unroll
                for (int e = 0; e < 8; ++e)
                    lV[(vseg + u * 8 + e) * 72 + vkey] = dv[u][e];
        }
        __syncthreads();

        // S = Q @ K^T  (16q x 64k per wave)
        f32x4 sa[4];
        #pragma unroll
        for (int kc = 0; kc < 4; ++kc) {
            sa[kc] = f32x4{0.f, 0.f, 0.f, 0.f};
            #pragma unroll
            for (int kd = 0; kd < 6; ++kd) {
                bf16x8 kf = *(const bf16x8*)(&lK[(kc * 16 + l15) * 200 + kd * 32 + l4 * 8]);
                sa[kc] = __builtin_amdgcn_mfma_f32_16x16x32_bf16(qfr[kd], kf, sa[kc], 0, 0, 0);
            }
            sa[kc] *= scale;
        }
        // online softmax
        float fac[4], psum[4];
        #pragma unroll
        for (int jj = 0; jj < 4; ++jj) {
            float mx = fmaxf(fmaxf(sa[0][jj], sa[1][jj]), fmaxf(sa[2][jj], sa[3][jj]));
            #pragma unroll
            for (int off = 1; off <= 8; off <<= 1) mx = fmaxf(mx, __shfl_xor(mx, off));
            float mnew = fmaxf(m[jj], mx);
            fac[jj] = __expf(m[jj] - mnew);
            m[jj] = mnew;
            psum[jj] = 0.f;
        }
        #pragma unroll
        for (int kc = 0; kc < 4; ++kc) {
            #pragma unroll
            for (int jj = 0; jj < 4; ++jj) {
                float p = __expf(sa[kc][jj] - m[jj]);
                psum[jj] += p;
                lP[(wid * 16 + l4 * 4 + jj) * 72 + kc * 16 + l15] = f2bf(p);
            }
        }
        #pragma unroll
        for (int jj = 0; jj < 4; ++jj) {
            #pragma unroll
            for (int off = 1; off <= 8; off <<= 1) psum[jj] += __shfl_xor(psum[jj], off);
            l[jj] = l[jj] * fac[jj] + psum[jj];
        }
        #pragma unroll
        for (int nc = 0; nc < 8; ++nc)
            #pragma unroll
            for (int jj = 0; jj < 4; ++jj) acc_o[nc][jj] *= fac[jj];
        // O += P @ V
        #pragma unroll
        for (int kc2 = 0; kc2 < 2; ++kc2) {
            bf16x8 pf = *(const bf16x8*)(&lP[(wid * 16 + l15) * 72 + kc2 * 32 + l4 * 8]);
            #pragma unroll
            for (int nc = 0; nc < 8; ++nc) {
                bf16x8 vf = *(const bf16x8*)(&lV[(nc * 16 + l15) * 72 + kc2 * 32 + l4 * 8]);
                acc_o[nc] = __builtin_amdgcn_mfma_f32_16x16x32_bf16(pf, vf, acc_o[nc], 0, 0, 0);
            }
        }
        __syncthreads();
    }
    int row = qt * 64 + wid * 16 + l4 * 4;
    #pragma unroll
    for (int nc = 0; nc < 8; ++nc)
        #pragma unroll
        for (int jj = 0; jj < 4; ++jj) {
            float v = acc_o[nc][jj] / l[jj];
            attn_out[(long)(row + jj) * (NH * DV) + h * DV + nc * 16 + l15] = f2bf(v);
        }
}

// ---------------- launch ----------------
extern "C" void kernel_launch(void* const* d_in, const int* in_sizes, int n_in,
                              void* d_out, int out_size, void* d_ws, size_t ws_size,
                              hipStream_t stream) {
    const float* hs      = (const float*)d_in[0];
    const int*   pos     = (const int*)d_in[1];
    const int*   dsa     = (const int*)d_in[2];
    const float* wq_a    = (const float*)d_in[3];
    const float* q_ln    = (const float*)d_in[4];
    const float* wq_b    = (const float*)d_in[5];
    const float* wq_rope = (const float*)d_in[6];
    const float* wkv_a   = (const float*)d_in[7];
    const float* kv_ln   = (const float*)d_in[8];
    const float* wkv_b   = (const float*)d_in[9];
    const float* wo      = (const float*)d_in[10];
    float* out = (float*)d_out;

    char* ws = (char*)d_ws;
    auto alloc = [&](size_t bytes) {
        char* p = ws; ws += (bytes + 255) & ~(size_t)255; return p;
    };
    u16* W1t  = (u16*)alloc(1344L * 2048 * 2);  // [wq_a_t ; wkv_a_t]
    u16* W2t  = (u16*)alloc(3072L * 768 * 2);   // [wq_b_t ; wq_rope_t]
    u16* W3t  = (u16*)alloc(4096L * 512 * 2);   // wkv_b_t
    u16* W4t  = (u16*)alloc(2048L * 2048 * 2);  // wo_t
    float* q_lr  = (float*)alloc(4096L * 768 * 4);
    float* kv_lr = (float*)alloc(4096L * 576 * 4);
    u16* q_latent   = (u16*)alloc(4096L * 768 * 2);
    u16* kv_latent  = (u16*)alloc(4096L * 512 * 2);
    u16* q_rope_raw = (u16*)alloc(4096L * 1024 * 2);
    u16* q_full     = (u16*)alloc(16L * 4096 * 192 * 2);
    u16* k_buf      = (u16*)alloc(16L * 4096 * 128 * 2);
    u16* v_buf      = (u16*)alloc(16L * 4096 * 128 * 2);
    float* cos_t    = (float*)alloc(4096L * 32 * 4);
    float* sin_t    = (float*)alloc(4096L * 32 * 4);
    // Union region: hs_bf16 (16.8MB, dead after G1) overlaps k_g/v_g/krope
    // (written only after G1/G3 complete).
    char* late = alloc(16L * 4096 * 2 * 2 > (16L * 1024 * 192 + 16L * 1024 * 128 + 4096L * 64) * 2
                       ? 16L * 4096 * 2 * 2
                       : (16L * 1024 * 192 + 16L * 1024 * 128 + 4096L * 64) * 2);
    u16* hs_bf = (u16*)late;                       // 4096*2048 bf16
    u16* k_g   = (u16*)late;                       // 16*1024*192
    u16* v_g   = k_g + 16L * 1024 * 192;           // 16*1024*128
    u16* krope = v_g + 16L * 1024 * 128;           // 4096*64
    // attn output aliases q_lr+kv_lr region (dead by then): 16.8MB <= 22MB
    u16* attn_o = (u16*)q_lr;

    k_yarn<<<dim3(512), dim3(256), 0, stream>>>(pos, cos_t, sin_t);
    k_cast<<<dim3(8192), dim3(256), 0, stream>>>(hs, hs_bf, 4096 * 2048 / 4);

    k_transpose<<<dim3(768 / 32, 2048 / 32), 256, 0, stream>>>(wq_a, W1t, 2048, 768);
    k_transpose<<<dim3(576 / 32, 2048 / 32), 256, 0, stream>>>(wkv_a, W1t + 768L * 2048, 2048, 576);
    k_transpose<<<dim3(2048 / 32, 768 / 32), 256, 0, stream>>>(wq_b, W2t, 768, 2048);
    k_transpose<<<dim3(1024 / 32, 768 / 32), 256, 0, stream>>>(wq_rope, W2t + 2048L * 768, 768, 1024);
    k_transpose<<<dim3(4096 / 32, 512 / 32), 256, 0, stream>>>(wkv_b, W3t, 512, 4096);
    k_transpose<<<dim3(2048 / 32, 2048 / 32), 256, 0, stream>>>(wo, W4t, 2048, 2048);

    // G1: hs @ [wq_a|wkv_a]  (M=4096, N=1344, K=2048) -> q_lr, kv_lr (fp32)
    k_gemm<0><<<dim3(11, 32), 256, 0, stream>>>(hs_bf, W1t, q_lr, kv_lr, 4096, 1344, 2048);
    k_rms_q<<<4096, 256, 0, stream>>>(q_lr, q_ln, q_latent);
    k_kv_norm_rope<<<4096, 256, 0, stream>>>(kv_lr, kv_ln, cos_t, sin_t, kv_latent, krope);
    // G2: q_latent @ [wq_b|wq_rope]  (N=3072, K=768) -> q_full(d<128), q_rope_raw
    k_gemm<1><<<dim3(24, 32), 256, 0, stream>>>(q_latent, W2t, q_full, q_rope_raw, 4096, 3072, 768);
    k_rope_q<<<16384, 256, 0, stream>>>(q_rope_raw, cos_t, sin_t, q_full);
    // G3: kv_latent @ wkv_b  (N=4096, K=512) -> k_buf, v_buf
    k_gemm<2><<<dim3(32, 32), 256, 0, stream>>>(kv_latent, W3t, k_buf, v_buf, 4096, 4096, 512);
    k_gather<<<dim3(1024, 16), 64, 0, stream>>>(dsa, k_buf, v_buf, krope, k_g, v_g);
    k_attn<<<dim3(64, 16), 256, 0, stream>>>(q_full, k_g, v_g, attn_o);
    // G4: attn @ wo  (N=2048, K=2048) -> out (fp32)
    k_gemm<3><<<dim3(16, 32), 256, 0, stream>>>(attn_o, W4t, out, nullptr, 4096, 2048, 2048);
}

// Round 8
// 502.421 us; speedup vs baseline: 1.0225x; 1.0225x over previous
//
#include <hip/hip_runtime.h>
#include <hip/hip_bf16.h>
#include <math.h>

#define S_LEN 4096
#define HIDDEN 2048
#define NH 16
#define QLORA 768
#define KVLORA 512
#define DROPE 64
#define DV 128
#define TOPK 1024
#define DQK 192

typedef __attribute__((ext_vector_type(4))) float f32x4;
typedef __attribute__((ext_vector_type(8))) __bf16 bf16x8;
typedef unsigned short u16;
typedef unsigned int u32;

__device__ __forceinline__ u16 f2bf(float f) {
    union { float f; u32 u; } v; v.f = f;
    u32 r = v.u + 0x7fffu + ((v.u >> 16) & 1u);
    return (u16)(r >> 16);
}

// async global->LDS 16B: per-lane global src, wave-uniform LDS base (+lane*16 implied)
__device__ __forceinline__ void gll16(const u16* g, u16* l) {
    __builtin_amdgcn_global_load_lds((const void*)g, (void*)l, 16, 0, 0);
}

// ---------------- fp32 -> bf16 cast (hidden_states) ----------------
__global__ __launch_bounds__(256) void k_cast(const float* __restrict__ src,
                                              u16* __restrict__ dst, int n4) {
    int i = blockIdx.x * 256 + threadIdx.x;
    if (i >= n4) return;
    float4 v = ((const float4*)src)[i];
    union { u16 h[4]; uint2 u; } o;
    o.h[0] = f2bf(v.x); o.h[1] = f2bf(v.y);
    o.h[2] = f2bf(v.z); o.h[3] = f2bf(v.w);
    ((uint2*)dst)[i] = o.u;
}

// ---------------- YaRN cos/sin table ----------------
__global__ __launch_bounds__(256) void k_yarn(const int* __restrict__ pos_ids,
                                              float* __restrict__ cos_t,
                                              float* __restrict__ sin_t) {
    int idx = blockIdx.x * 256 + threadIdx.x;     // S*32 entries
    if (idx >= S_LEN * 32) return;
    int s = idx >> 5, i = idx & 31;
    float pos = (float)pos_ids[s];
    float inv = expf(-(float)i * 0.503690489092448f) * (1.0f / 1024.0f);
    float ang = pos * inv;
    const float MS2 = 1.8132604f;                 // (0.1*ln(32)+1)^2
    float sv, cv;
    sincosf(ang, &sv, &cv);
    cos_t[idx] = cv * MS2;
    sin_t[idx] = sv * MS2;
}

// ---------------- weight transpose+cast  W[K,N] fp32 -> Wt[N,K] bf16 ----------------
__global__ __launch_bounds__(256) void k_transpose(const float* __restrict__ src,
                                                   u16* __restrict__ dst,
                                                   int K, int N) {
    __shared__ u16 t[32][33];
    int n0 = blockIdx.x * 32, k0 = blockIdx.y * 32;
    int tx = threadIdx.x & 31, ty = threadIdx.x >> 5;   // 32 x 8
    #pragma unroll
    for (int i = 0; i < 32; i += 8)
        t[ty + i][tx] = f2bf(src[(long)(k0 + ty + i) * N + n0 + tx]);
    __syncthreads();
    #pragma unroll
    for (int i = 0; i < 32; i += 8)
        dst[(long)(n0 + ty + i) * K + k0 + tx] = t[tx][ty + i];
}

// ---------------- m97-style bf16 GEMM: C = A[M,K] @ Bt[N,K]^T ----------------
// 128x128 tile, BK=32, global_load_lds staging, linear LDS [128][32].
// MODE 0: G1  col<768 -> q_lr fp32; col<1344 -> kv_lr fp32; else (pad) skip
// MODE 1: G2  col<2048 -> q_full nope part; else fused YaRN RoPE -> q_full rope part
// MODE 2: G3  k/v split -> k_buf / v_buf bf16 [h][s][128]
// MODE 3: G4  fp32 row-major out
template <int MODE>
__global__ __launch_bounds__(256) void k_gemm(const u16* __restrict__ A,
                                              const u16* __restrict__ Bt,
                                              void* __restrict__ out0,
                                              void* __restrict__ out1,
                                              const float* __restrict__ cos_t,
                                              const float* __restrict__ sin_t,
                                              int M, int N, int K) {
    __shared__ u16 lA[128 * 32];
    __shared__ u16 lB[128 * 32];
    const int bm = blockIdx.y, bn = blockIdx.x;
    const int tid = threadIdx.x;
    const int lane = tid & 63, wid = tid >> 6;
    const int wr = wid >> 1, wc = wid & 1;
    const int l15 = lane & 15, l4 = lane >> 4;

    f32x4 acc[4][4];
    #pragma unroll
    for (int i = 0; i < 4; ++i)
        #pragma unroll
        for (int j = 0; j < 4; ++j) acc[i][j] = f32x4{0.f, 0.f, 0.f, 0.f};

    // staging: wave w covers rows [w*32, w*32+32) via 2 instrs of 16 rows
    const int srow = wid * 32 + (lane >> 2);
    const int scol = (lane & 3) * 8;
    const u16* gA = A + (long)(bm * 128 + srow) * K + scol;
    const u16* gB = Bt + (long)(bn * 128 + srow) * K + scol;
    u16* lA0 = lA + wid * 1024;            // (w*32)*32
    u16* lB0 = lB + wid * 1024;
    const long kstep16 = 16L * K;

    const int nkt = K >> 5;
    for (int kt = 0; kt < nkt; ++kt) {
        const u16* pa = gA + kt * 32;
        const u16* pb = gB + kt * 32;
        gll16(pa, lA0);
        gll16(pa + kstep16, lA0 + 512);
        gll16(pb, lB0);
        gll16(pb + kstep16, lB0 + 512);
        __syncthreads();

        bf16x8 af[4], bfr[4];
        #pragma unroll
        for (int mr = 0; mr < 4; ++mr)
            af[mr] = *(const bf16x8*)(&lA[(wr * 64 + mr * 16 + l15) * 32 + l4 * 8]);
        #pragma unroll
        for (int nc = 0; nc < 4; ++nc)
            bfr[nc] = *(const bf16x8*)(&lB[(wc * 64 + nc * 16 + l15) * 32 + l4 * 8]);
        #pragma unroll
        for (int mr = 0; mr < 4; ++mr)
            #pragma unroll
            for (int nc = 0; nc < 4; ++nc)
                acc[mr][nc] = __builtin_amdgcn_mfma_f32_16x16x32_bf16(
                    af[mr], bfr[nc], acc[mr][nc], 0, 0, 0);
        __syncthreads();
    }

    const int row0 = bm * 128 + wr * 64;
    const int col0 = bn * 128 + wc * 64;
    #pragma unroll
    for (int mr = 0; mr < 4; ++mr) {
        #pragma unroll
        for (int nc = 0; nc < 4; ++nc) {
            #pragma unroll
            for (int jj = 0; jj < 4; ++jj) {
                int row = row0 + mr * 16 + l4 * 4 + jj;
                int col = col0 + nc * 16 + l15;
                float v = acc[mr][nc][jj];
                if (MODE == 0) {
                    if (col < QLORA)
                        ((float*)out0)[(long)row * QLORA + col] = v;
                    else if (col < QLORA + KVLORA + DROPE)
                        ((float*)out1)[(long)row * (KVLORA + DROPE) + (col - QLORA)] = v;
                } else if (MODE == 1) {
                    if (col < NH * DV) {
                        int h = col >> 7, d = col & 127;
                        ((u16*)out0)[((long)h * S_LEN + row) * DQK + d] = f2bf(v);
                    } else {
                        // fused YaRN RoPE: partner j^32 lives at acc[mr][nc^2][jj]
                        int c2 = col - NH * DV;
                        int h = c2 >> 6, j = c2 & 63, i = j & 31;
                        float c = cos_t[row * 32 + i], sn = sin_t[row * 32 + i];
                        float xp = acc[mr][nc ^ 2][jj];
                        float val = (j < 32) ? v * c - xp * sn : v * c + xp * sn;
                        ((u16*)out0)[((long)h * S_LEN + row) * DQK + DV + j] = f2bf(val);
                    }
                } else if (MODE == 2) {
                    int h = col >> 8, rr = col & 255;
                    if (rr < 128)
                        ((u16*)out0)[((long)h * S_LEN + row) * DV + rr] = f2bf(v);
                    else
                        ((u16*)out1)[((long)h * S_LEN + row) * DV + (rr - 128)] = f2bf(v);
                } else {
                    ((float*)out0)[(long)row * N + col] = v;
                }
            }
        }
    }
}

// ---------------- RMSNorm (q path, C=768) ----------------
__global__ __launch_bounds__(256) void k_rms_q(const float* __restrict__ q_lr,
                                               const float* __restrict__ w,
                                               u16* __restrict__ q_latent) {
    int s = blockIdx.x;
    const float* x = q_lr + (long)s * QLORA;
    int t = threadIdx.x;
    float v0 = x[t], v1 = x[t + 256], v2 = x[t + 512];
    float ss = v0 * v0 + v1 * v1 + v2 * v2;
    #pragma unroll
    for (int off = 32; off >= 1; off >>= 1) ss += __shfl_xor(ss, off);
    __shared__ float red[4];
    if ((t & 63) == 0) red[t >> 6] = ss;
    __syncthreads();
    ss = red[0] + red[1] + red[2] + red[3];
    float inv = rsqrtf(ss / (float)QLORA + 1e-6f);
    u16* o = q_latent + (long)s * QLORA;
    o[t]       = f2bf(v0 * inv * w[t]);
    o[t + 256] = f2bf(v1 * inv * w[t + 256]);
    o[t + 512] = f2bf(v2 * inv * w[t + 512]);
}

// ---------------- RMSNorm (kv, C=512) + k_rope rotation ----------------
__global__ __launch_bounds__(256) void k_kv_norm_rope(const float* __restrict__ kv_lr,
                                                      const float* __restrict__ w,
                                                      const float* __restrict__ cos_t,
                                                      const float* __restrict__ sin_t,
                                                      u16* __restrict__ kv_latent,
                                                      u16* __restrict__ krope) {
    int s = blockIdx.x;
    const float* x = kv_lr + (long)s * (KVLORA + DROPE);
    int t = threadIdx.x;
    float v0 = x[t], v1 = x[t + 256];
    float ss = v0 * v0 + v1 * v1;
    #pragma unroll
    for (int off = 32; off >= 1; off >>= 1) ss += __shfl_xor(ss, off);
    __shared__ float red[4];
    if ((t & 63) == 0) red[t >> 6] = ss;
    __syncthreads();
    ss = red[0] + red[1] + red[2] + red[3];
    float inv = rsqrtf(ss / (float)KVLORA + 1e-6f);
    u16* o = kv_latent + (long)s * KVLORA;
    o[t]       = f2bf(v0 * inv * w[t]);
    o[t + 256] = f2bf(v1 * inv * w[t + 256]);
    if (t < DROPE) {
        int i = t & 31;
        float c = cos_t[s * 32 + i], sn = sin_t[s * 32 + i];
        float xr = x[KVLORA + t];
        float xp = x[KVLORA + ((t < 32) ? t + 32 : t - 32)];
        float val = (t < 32) ? xr * c - xp * sn : xr * c + xp * sn;
        krope[(long)s * DROPE + t] = f2bf(val);
    }
}

// ---------------- gather: k_g row-major [h][j][192], v_g_t transposed [h][kt][d][64] ----------------
__global__ void k_gather(const int* __restrict__ idx,
                         const u16* __restrict__ k_buf,
                         const u16* __restrict__ v_buf,
                         const u16* __restrict__ krope,
                         u16* __restrict__ k_g, u16* __restrict__ v_g_t) {
    int j = blockIdx.x, h = blockIdx.y, t = threadIdx.x;  // 64 threads
    int src = idx[j];
    const uint4* kb = (const uint4*)(k_buf + ((long)h * S_LEN + src) * DV);
    const uint4* kr = (const uint4*)(krope + (long)src * DROPE);
    uint4* kgp = (uint4*)(k_g + ((long)h * TOPK + j) * DQK);
    if (t < 16)       kgp[t] = kb[t];
    else if (t < 24)  kgp[t] = kr[t - 16];
    // V transposed: thread t handles d = 2t, 2t+1 for key j
    u32 vv = *(const u32*)(v_buf + ((long)h * S_LEN + src) * DV + t * 2);
    int kt = j >> 6, jin = j & 63;
    u16* base = v_g_t + ((long)(h * 16 + kt) * 128) * 64 + jin;
    base[(2 * t) * 64]     = (u16)(vv & 0xffff);
    base[(2 * t + 1) * 64] = (u16)(vv >> 16);
}

// ---------------- flash attention over gathered keys ----------------
// grid 512: each block = 128 q-rows of one head; 4 waves x 32 q (2 sub-tiles of 16).
// XCD-aware: blockIdx%8 = XCD -> heads {2x,2x+1} pinned per XCD for L2 locality.
__global__ __launch_bounds__(256) void k_attn(const u16* __restrict__ qf,
                                              const u16* __restrict__ kg,
                                              const u16* __restrict__ vgt,
                                              u16* __restrict__ attn_out) {
    __shared__ u16 lK[64 * 200];     // [key][192 pad->200]
    __shared__ u16 lVt[128 * 72];    // [d][64 keys pad->72]
    __shared__ u16 lP[4][16 * 72];   // per-wave [q16][64 keys pad->72]
    const int b = blockIdx.x;
    const int h = (b & 7) * 2 + ((b >> 3) & 1);
    const int qt = b >> 4;           // 0..31
    const int tid = threadIdx.x, lane = tid & 63, wid = tid >> 6;
    const int l15 = lane & 15, l4 = lane >> 4;

    bf16x8 qfr[2][6];
    #pragma unroll
    for (int qs = 0; qs < 2; ++qs) {
        const u16* qrow = qf + ((long)h * S_LEN + qt * 128 + wid * 32 + qs * 16 + l15) * DQK + l4 * 8;
        #pragma unroll
        for (int kd = 0; kd < 6; ++kd) qfr[qs][kd] = *(const bf16x8*)(qrow + kd * 32);
    }
    float m[2][4], l[2][4];
    #pragma unroll
    for (int qs = 0; qs < 2; ++qs)
        #pragma unroll
        for (int jj = 0; jj < 4; ++jj) { m[qs][jj] = -1e30f; l[qs][jj] = 0.f; }
    f32x4 acc_o[2][8];
    #pragma unroll
    for (int qs = 0; qs < 2; ++qs)
        #pragma unroll
        for (int nc = 0; nc < 8; ++nc) acc_o[qs][nc] = f32x4{0.f, 0.f, 0.f, 0.f};

    const int krow = tid >> 2, kseg = (tid & 3) * 48;
    u16* lPw = lP[wid];
    const float scale = 0.07216878364870323f;  // 1/sqrt(192)

    for (int kt = 0; kt < TOPK / 64; ++kt) {
        {   // K tile (row-major, b128)
            const u16* src = kg + ((long)h * TOPK + kt * 64 + krow) * DQK + kseg;
            u16* dst = &lK[krow * 200 + kseg];
            #pragma unroll
            for (int u = 0; u < 6; ++u)
                *(uint4*)(dst + u * 8) = *(const uint4*)(src + u * 8);
        }
        {   // V^T tile (already transposed in global; pure row copies)
            const u16* src = vgt + ((long)(h * 16 + kt) * 128) * 64 + tid * 32;
            u16* dst = &lVt[(tid >> 1) * 72 + (tid & 1) * 32];
            #pragma unroll
            for (int c = 0; c < 4; ++c)
                *(uint4*)(dst + c * 8) = *(const uint4*)(src + c * 8);
        }
        __syncthreads();

        #pragma unroll
        for (int qs = 0; qs < 2; ++qs) {
            // S = Q @ K^T  (16q x 64k)
            f32x4 sa[4];
            #pragma unroll
            for (int kc = 0; kc < 4; ++kc) {
                sa[kc] = f32x4{0.f, 0.f, 0.f, 0.f};
                #pragma unroll
                for (int kd = 0; kd < 6; ++kd) {
                    bf16x8 kf = *(const bf16x8*)(&lK[(kc * 16 + l15) * 200 + kd * 32 + l4 * 8]);
                    sa[kc] = __builtin_amdgcn_mfma_f32_16x16x32_bf16(qfr[qs][kd], kf, sa[kc], 0, 0, 0);
                }
                sa[kc] *= scale;
            }
            // online softmax (rows q = l4*4+jj, keys over kc,l15)
            float fac[4], psum[4];
            #pragma unroll
            for (int jj = 0; jj < 4; ++jj) {
                float mx = fmaxf(fmaxf(sa[0][jj], sa[1][jj]), fmaxf(sa[2][jj], sa[3][jj]));
                #pragma unroll
                for (int off = 1; off <= 8; off <<= 1) mx = fmaxf(mx, __shfl_xor(mx, off));
                float mnew = fmaxf(m[qs][jj], mx);
                fac[jj] = __expf(m[qs][jj] - mnew);
                m[qs][jj] = mnew;
                psum[jj] = 0.f;
            }
            #pragma unroll
            for (int kc = 0; kc < 4; ++kc) {
                #pragma unroll
                for (int jj = 0; jj < 4; ++jj) {
                    float p = __expf(sa[kc][jj] - m[qs][jj]);
                    psum[jj] += p;
                    lPw[(l4 * 4 + jj) * 72 + kc * 16 + l15] = f2bf(p);
                }
            }
            #pragma unroll
            for (int jj = 0; jj < 4; ++jj) {
                #pragma unroll
                for (int off = 1; off <= 8; off <<= 1) psum[jj] += __shfl_xor(psum[jj], off);
                l[qs][jj] = l[qs][jj] * fac[jj] + psum[jj];
            }
            #pragma unroll
            for (int nc = 0; nc < 8; ++nc)
                #pragma unroll
                for (int jj = 0; jj < 4; ++jj) acc_o[qs][nc][jj] *= fac[jj];
            // O += P @ V  (A=P from lPw rows, B=V^T from lVt rows)
            #pragma unroll
            for (int kc2 = 0; kc2 < 2; ++kc2) {
                bf16x8 pf = *(const bf16x8*)(&lPw[l15 * 72 + kc2 * 32 + l4 * 8]);
                #pragma unroll
                for (int nc = 0; nc < 8; ++nc) {
                    bf16x8 vf = *(const bf16x8*)(&lVt[(nc * 16 + l15) * 72 + kc2 * 32 + l4 * 8]);
                    acc_o[qs][nc] = __builtin_amdgcn_mfma_f32_16x16x32_bf16(pf, vf, acc_o[qs][nc], 0, 0, 0);
                }
            }
        }
        __syncthreads();
    }
    #pragma unroll
    for (int qs = 0; qs < 2; ++qs) {
        int row = qt * 128 + wid * 32 + qs * 16 + l4 * 4;
        #pragma unroll
        for (int nc = 0; nc < 8; ++nc)
            #pragma unroll
            for (int jj = 0; jj < 4; ++jj) {
                float v = acc_o[qs][nc][jj] / l[qs][jj];
                attn_out[(long)(row + jj) * (NH * DV) + h * DV + nc * 16 + l15] = f2bf(v);
            }
    }
}

// ---------------- launch ----------------
extern "C" void kernel_launch(void* const* d_in, const int* in_sizes, int n_in,
                              void* d_out, int out_size, void* d_ws, size_t ws_size,
                              hipStream_t stream) {
    const float* hs      = (const float*)d_in[0];
    const int*   pos     = (const int*)d_in[1];
    const int*   dsa     = (const int*)d_in[2];
    const float* wq_a    = (const float*)d_in[3];
    const float* q_ln    = (const float*)d_in[4];
    const float* wq_b    = (const float*)d_in[5];
    const float* wq_rope = (const float*)d_in[6];
    const float* wkv_a   = (const float*)d_in[7];
    const float* kv_ln   = (const float*)d_in[8];
    const float* wkv_b   = (const float*)d_in[9];
    const float* wo      = (const float*)d_in[10];
    float* out = (float*)d_out;

    char* ws = (char*)d_ws;
    auto alloc = [&](size_t bytes) {
        char* p = ws; ws += (bytes + 255) & ~(size_t)255; return p;
    };
    u16* W1t  = (u16*)alloc(1408L * 2048 * 2);  // [wq_a_t ; wkv_a_t], padded to 11*128 rows
    u16* W2t  = (u16*)alloc(3072L * 768 * 2);   // [wq_b_t ; wq_rope_t]
    u16* W3t  = (u16*)alloc(4096L * 512 * 2);   // wkv_b_t
    u16* W4t  = (u16*)alloc(2048L * 2048 * 2);  // wo_t
    float* q_lr  = (float*)alloc(4096L * 768 * 4);
    float* kv_lr = (float*)alloc(4096L * 576 * 4);
    u16* q_latent   = (u16*)alloc(4096L * 768 * 2);
    u16* kv_latent  = (u16*)alloc(4096L * 512 * 2);
    u16* q_full     = (u16*)alloc(16L * 4096 * 192 * 2);
    u16* k_buf      = (u16*)alloc(16L * 4096 * 128 * 2);
    u16* v_buf      = (u16*)alloc(16L * 4096 * 128 * 2);
    float* cos_t    = (float*)alloc(4096L * 32 * 4);
    float* sin_t    = (float*)alloc(4096L * 32 * 4);
    // Union: hs_bf16 (16.8MB, dead after G1) overlaps k_g/v_g_t/krope (11MB, written post-G3).
    char* late = alloc(16L * 4096 * 2 * 2);
    u16* hs_bf = (u16*)late;                       // 4096*2048 bf16
    u16* k_g   = (u16*)late;                       // 16*1024*192
    u16* v_g_t = k_g + 16L * 1024 * 192;           // 16*16*128*64
    u16* krope = v_g_t + 16L * 1024 * 128;         // 4096*64
    // attn output aliases q_lr+kv_lr region (both dead by then)
    u16* attn_o = (u16*)q_lr;

    k_yarn<<<dim3(512), dim3(256), 0, stream>>>(pos, cos_t, sin_t);
    k_cast<<<dim3(8192), dim3(256), 0, stream>>>(hs, hs_bf, 4096 * 2048 / 4);

    k_transpose<<<dim3(768 / 32, 2048 / 32), 256, 0, stream>>>(wq_a, W1t, 2048, 768);
    k_transpose<<<dim3(576 / 32, 2048 / 32), 256, 0, stream>>>(wkv_a, W1t + 768L * 2048, 2048, 576);
    k_transpose<<<dim3(2048 / 32, 768 / 32), 256, 0, stream>>>(wq_b, W2t, 768, 2048);
    k_transpose<<<dim3(1024 / 32, 768 / 32), 256, 0, stream>>>(wq_rope, W2t + 2048L * 768, 768, 1024);
    k_transpose<<<dim3(4096 / 32, 512 / 32), 256, 0, stream>>>(wkv_b, W3t, 512, 4096);
    k_transpose<<<dim3(2048 / 32, 2048 / 32), 256, 0, stream>>>(wo, W4t, 2048, 2048);

    // G1: hs @ [wq_a|wkv_a]  (M=4096, N=1344->1408, K=2048) -> q_lr, kv_lr (fp32)
    k_gemm<0><<<dim3(11, 32), 256, 0, stream>>>(hs_bf, W1t, q_lr, kv_lr, nullptr, nullptr, 4096, 1408, 2048);
    k_rms_q<<<4096, 256, 0, stream>>>(q_lr, q_ln, q_latent);
    k_kv_norm_rope<<<4096, 256, 0, stream>>>(kv_lr, kv_ln, cos_t, sin_t, kv_latent, krope);
    // G2: q_latent @ [wq_b|wq_rope]  (N=3072, K=768) -> q_full (RoPE fused)
    k_gemm<1><<<dim3(24, 32), 256, 0, stream>>>(q_latent, W2t, q_full, nullptr, cos_t, sin_t, 4096, 3072, 768);
    // G3: kv_latent @ wkv_b  (N=4096, K=512) -> k_buf, v_buf
    k_gemm<2><<<dim3(32, 32), 256, 0, stream>>>(kv_latent, W3t, k_buf, v_buf, nullptr, nullptr, 4096, 4096, 512);
    k_gather<<<dim3(1024, 16), 64, 0, stream>>>(dsa, k_buf, v_buf, krope, k_g, v_g_t);
    k_attn<<<dim3(512), 256, 0, stream>>>(q_full, k_g, v_g_t, attn_o);
    // G4: attn @ wo  (N=2048, K=2048) -> out (fp32)
    k_gemm<3><<<dim3(16, 32), 256, 0, stream>>>(attn_o, W4t, out, nullptr, nullptr, nullptr, 4096, 2048, 2048);
}